// Round 2
// baseline (2387.361 us; speedup 1.0000x reference)
//
#include <hip/hip_runtime.h>
#include <cstdint>

// SelfMatchingLayer: B=32, L=512, H=256, fp32.
// R2: fix LDS-pipe-bound patterns everywhere.
//  - k1/k4/k5/k6: 64x64 output tiles, 8x8 per-thread register tiles,
//    [k][elem] LDS layout (stride 65), scalar conflict-free reads.
//  - k2: tanh identity  sum w*tanh(z) = C - 2*sum w/(1+e^{2z}); HQ/PP
//    pre-scaled by 2*log2(e) in k1; 8t x 2l register tile.
//  - k7: 2D split (8 rows x 32 k per thread) + shfl_xor butterfly reduce;
//    cuts per-step LDS from 384 b128 broadcasts to ~48 b128 + 84 bperm.

#define LL 512
#define HH 256

typedef _Float16 half2_t __attribute__((ext_vector_type(2)));

__device__ __forceinline__ float exp2f_fast(float x){
#if defined(__HIP_DEVICE_COMPILE__)
  return __builtin_amdgcn_exp2f(x);
#else
  return exp2f(x);
#endif
}
__device__ __forceinline__ float rcpf_fast(float x){
#if defined(__HIP_DEVICE_COMPILE__)
  return __builtin_amdgcn_rcpf(x);
#else
  return 1.0f/x;
#endif
}
__device__ __forceinline__ float tanh_fast(float x){
  float e = exp2f_fast(x * 2.885390081777927f);   // 2*log2(e)
  return 1.0f - 2.0f * rcpf_fast(1.0f + e);
}
__device__ __forceinline__ float sigmoid_fast(float x){
  return rcpf_fast(1.0f + exp2f_fast(x * -1.4426950408889634f));
}

#define SCALE_K2 2.885390081777927f   // 2*log2(e)

// ---- staging helpers: 64 rows x 64 k chunk of a row-major matrix ----
// stage_t: Ls[k*65 + r] = g[r*ldg + k]   (transpose into [k][elem])
__device__ __forceinline__ void stage_t(float* Ls, const float* g, int ldg){
  int tid = threadIdx.x;
  int r = tid >> 4; int kq = (tid & 15) * 4;
  #pragma unroll
  for (int it = 0; it < 4; it++){
    int rr = r + 16*it;
    float4 v = *(const float4*)(g + (size_t)rr*ldg + kq);
    Ls[(kq+0)*65 + rr] = v.x;
    Ls[(kq+1)*65 + rr] = v.y;
    Ls[(kq+2)*65 + rr] = v.z;
    Ls[(kq+3)*65 + rr] = v.w;
  }
}
// stage_d: Ls[r*65 + j] = g[r*ldg + j]   (direct, already [k][elem])
__device__ __forceinline__ void stage_d(float* Ls, const float* g, int ldg){
  int tid = threadIdx.x;
  int r = tid >> 4; int jq = (tid & 15) * 4;
  #pragma unroll
  for (int it = 0; it < 4; it++){
    int rr = r + 16*it;
    float4 v = *(const float4*)(g + (size_t)rr*ldg + jq);
    float* d = Ls + rr*65 + jq;
    d[0]=v.x; d[1]=v.y; d[2]=v.z; d[3]=v.w;
  }
}
// inner: acc[i][j] += sum_k Xs[k][rg+8i] * Ws[k][cg+8j]
__device__ __forceinline__ void rg_inner(const float* Xs, const float* Ws,
                                         float (&acc)[8][8], int rg, int cg){
  #pragma unroll 2
  for (int k = 0; k < 64; k++){
    float xv[8], wv[8];
    #pragma unroll
    for (int i=0;i<8;i++) xv[i] = Xs[k*65 + rg + 8*i];
    #pragma unroll
    for (int j=0;j<8;j++) wv[j] = Ws[k*65 + cg + 8*j];
    #pragma unroll
    for (int i=0;i<8;i++)
      #pragma unroll
      for (int j=0;j<8;j++)
        acc[i][j] = fmaf(xv[i], wv[j], acc[i][j]);
  }
}

// ---------------- K1: HQ' = SC*(P@wq^T + bq) ; PP' = SC*(P@wp^T + bp) ----
// grid (256 row-tiles, 8 col-tiles): ct<4 -> wq/HQ, else wp/PP.
__global__ __launch_bounds__(256) void k1_hq_pp(
    const float* __restrict__ P,
    const float* __restrict__ wq_w, const float* __restrict__ wq_b,
    const float* __restrict__ wp_w, const float* __restrict__ wp_b,
    float* __restrict__ HQ, float* __restrict__ PP)
{
  __shared__ float Xs[64*65];
  __shared__ float Ws[64*65];
  int rt = blockIdx.x, ct = blockIdx.y;
  const float* W  = (ct < 4) ? wq_w : wp_w;
  const float* Bv = (ct < 4) ? wq_b : wp_b;
  float* O = (ct < 4) ? HQ : PP;
  int c0 = (ct & 3) * 64, r0 = rt * 64;
  int tid = threadIdx.x, rg = tid & 7, cg = (tid >> 3) & 7;
  float acc[8][8];
  #pragma unroll
  for (int i=0;i<8;i++)
    #pragma unroll
    for (int j=0;j<8;j++) acc[i][j]=0.f;
  for (int kc = 0; kc < 4; kc++){
    __syncthreads();
    stage_t(Xs, P + (size_t)r0*HH + kc*64, HH);
    stage_t(Ws, W + (size_t)c0*HH + kc*64, HH);
    __syncthreads();
    rg_inner(Xs, Ws, acc, rg, cg);
  }
  float bj[8];
  #pragma unroll
  for (int j=0;j<8;j++) bj[j] = Bv[c0 + cg + 8*j];
  #pragma unroll
  for (int i=0;i<8;i++){
    int r = r0 + rg + 8*i;
    #pragma unroll
    for (int j=0;j<8;j++)
      O[(size_t)r*HH + c0 + cg + 8*j] = SCALE_K2 * (acc[i][j] + bj[j]);
  }
}

// ---------------- K2: S_eff[b,t,l] = -2 * sum_h w_h / (1 + exp2(HQ'+PP')) --
// (equals sum w*tanh up to softmax-invariant constant, sign included)
// grid (16 t-tiles, 32 b); 256 thr; per-thread 8t x 2l tile.
__global__ __launch_bounds__(256) void k2_scores(
    const float* __restrict__ HQ, const float* __restrict__ PP,
    const float* __restrict__ ws_w, float* __restrict__ S)
{
  __shared__ float Hq_c[128*65];
  __shared__ float Pp_c[32*65];
  __shared__ float wsl[256];
  int tid = threadIdx.x;
  int b = blockIdx.y, t0 = blockIdx.x * 32;
  wsl[tid] = ws_w[tid];
  int tg = tid >> 6;        // 0..3 (uniform per wave)
  int lg = tid & 63;        // 0..63
  for (int lc = 0; lc < 4; lc++){
    float acc[8][2];
    #pragma unroll
    for (int i=0;i<8;i++){ acc[i][0]=0.f; acc[i][1]=0.f; }
    for (int hc = 0; hc < 4; hc++){
      __syncthreads();
      // stage Pp chunk: 32 t x 64 h -> Pp_c[t][h]
      {
        int r = tid >> 4, kq = (tid & 15) * 4;
        #pragma unroll
        for (int it=0; it<2; it++){
          int t = r + 16*it;
          float4 v = *(const float4*)(PP + ((size_t)b*LL + t0 + t)*HH + hc*64 + kq);
          float* d = Pp_c + t*65 + kq;
          d[0]=v.x; d[1]=v.y; d[2]=v.z; d[3]=v.w;
        }
      }
      // stage Hq chunk: 128 l x 64 h -> Hq_c[l][h]
      {
        int r = tid >> 4, kq = (tid & 15) * 4;
        #pragma unroll
        for (int it=0; it<8; it++){
          int l = r + 16*it;
          float4 v = *(const float4*)(HQ + ((size_t)b*LL + lc*128 + l)*HH + hc*64 + kq);
          float* d = Hq_c + l*65 + kq;
          d[0]=v.x; d[1]=v.y; d[2]=v.z; d[3]=v.w;
        }
      }
      __syncthreads();
      #pragma unroll 2
      for (int h = 0; h < 64; h++){
        float w = wsl[hc*64 + h];
        float pp[8], hq[2];
        #pragma unroll
        for (int i=0;i<8;i++) pp[i] = Pp_c[(tg + 4*i)*65 + h];
        #pragma unroll
        for (int j=0;j<2;j++) hq[j] = Hq_c[(2*lg + j)*65 + h];
        #pragma unroll
        for (int i=0;i<8;i++)
          #pragma unroll
          for (int j=0;j<2;j++){
            float e = exp2f_fast(pp[i] + hq[j]);
            acc[i][j] = fmaf(w, rcpf_fast(1.0f + e), acc[i][j]);
          }
      }
    }
    #pragma unroll
    for (int i=0;i<8;i++)
      #pragma unroll
      for (int j=0;j<2;j++)
        S[((size_t)b*LL + t0 + tg + 4*i)*LL + lc*128 + 2*lg + j] = -2.0f*acc[i][j];
    __syncthreads();
  }
}

// ---------------- K3: softmax over l, in place; one wave per row ----------
__global__ __launch_bounds__(256) void k3_softmax(float* __restrict__ S)
{
  int wave = threadIdx.x >> 6, lane = threadIdx.x & 63;
  size_t row = (size_t)blockIdx.x*4 + wave;
  float* p = S + row*LL;
  float v[8];
  #pragma unroll
  for (int i=0;i<8;i++) v[i] = p[lane + 64*i];
  float m = v[0];
  #pragma unroll
  for (int i=1;i<8;i++) m = fmaxf(m, v[i]);
  #pragma unroll
  for (int off=32; off>=1; off>>=1) m = fmaxf(m, __shfl_xor(m, off, 64));
  float s = 0.f;
  #pragma unroll
  for (int i=0;i<8;i++){ v[i] = exp2f_fast((v[i]-m)*1.4426950408889634f); s += v[i]; }
  #pragma unroll
  for (int off=32; off>=1; off>>=1) s += __shfl_xor(s, off, 64);
  float inv = 1.0f / s;
  #pragma unroll
  for (int i=0;i<8;i++) p[lane + 64*i] = v[i]*inv;
}

// ---------------- K4: C[b,t,:] = attn[b,t,:] @ P[b,:,:] -------------------
// grid (4 j-tiles, 8 t-tiles, 32 b). K = l = 512 in 8 chunks.
__global__ __launch_bounds__(256) void k4_context(
    const float* __restrict__ S, const float* __restrict__ P, float* __restrict__ C)
{
  __shared__ float As[64*65];
  __shared__ float Ps[64*65];
  int j0 = blockIdx.x * 64, t0 = blockIdx.y * 64, b = blockIdx.z;
  int tid = threadIdx.x, rg = tid & 7, cg = (tid >> 3) & 7;
  float acc[8][8];
  #pragma unroll
  for (int i=0;i<8;i++)
    #pragma unroll
    for (int j=0;j<8;j++) acc[i][j]=0.f;
  for (int lc = 0; lc < 8; lc++){
    int l0 = lc*64;
    __syncthreads();
    stage_t(As, S + ((size_t)b*LL + t0)*LL + l0, LL);   // As[l][t]
    stage_d(Ps, P + ((size_t)b*LL + l0)*HH + j0, HH);   // Ps[l][j]
    __syncthreads();
    rg_inner(As, Ps, acc, rg, cg);
  }
  #pragma unroll
  for (int i=0;i<8;i++){
    int t = t0 + rg + 8*i;
    #pragma unroll
    for (int j=0;j<8;j++)
      C[((size_t)b*LL + t)*HH + j0 + cg + 8*j] = acc[i][j];
  }
}

// ---------------- K5: Cg = sigmoid([P|C]@wg^T + bg) * C -------------------
// grid (256 row-tiles, 4 col-tiles). K = 512 (P cols then C cols).
__global__ __launch_bounds__(256) void k5_gate(
    const float* __restrict__ P, const float* __restrict__ C,
    const float* __restrict__ wg_w, const float* __restrict__ wg_b,
    float* __restrict__ CG)
{
  __shared__ float Xs[64*65];
  __shared__ float Ws[64*65];
  int rt = blockIdx.x, ct = blockIdx.y;
  int r0 = rt*64, c0 = ct*64;
  int tid = threadIdx.x, rg = tid & 7, cg = (tid >> 3) & 7;
  float acc[8][8];
  #pragma unroll
  for (int i=0;i<8;i++)
    #pragma unroll
    for (int j=0;j<8;j++) acc[i][j]=0.f;
  for (int kc = 0; kc < 8; kc++){
    const float* Xsrc = (kc < 4) ? (P + (size_t)r0*HH + kc*64)
                                 : (C + (size_t)r0*HH + (kc-4)*64);
    __syncthreads();
    stage_t(Xs, Xsrc, HH);
    stage_t(Ws, wg_w + (size_t)c0*(2*HH) + kc*64, 2*HH);
    __syncthreads();
    rg_inner(Xs, Ws, acc, rg, cg);
  }
  float bj[8];
  #pragma unroll
  for (int j=0;j<8;j++) bj[j] = wg_b[c0 + cg + 8*j];
  #pragma unroll
  for (int i=0;i<8;i++){
    int r = r0 + rg + 8*i;
    #pragma unroll
    for (int j=0;j<8;j++){
      int c = c0 + cg + 8*j;
      float g = sigmoid_fast(acc[i][j] + bj[j]);
      CG[(size_t)r*HH + c] = g * C[(size_t)r*HH + c];
    }
  }
}

// ---------------- K6: GI_{l,r} = Cg @ Wih^T + bih -------------------------
// grid (256 row-tiles, 24 col-tiles): ct<12 -> left dir, else right.
__global__ __launch_bounds__(256) void k6_gi(
    const float* __restrict__ CG,
    const float* __restrict__ Wih_l, const float* __restrict__ bih_l,
    const float* __restrict__ Wih_r, const float* __restrict__ bih_r,
    float* __restrict__ GIL, float* __restrict__ GIR)
{
  __shared__ float Xs[64*65];
  __shared__ float Ws[64*65];
  int rt = blockIdx.x, ct = blockIdx.y;
  int dir = (ct >= 12);
  const float* Wih = dir ? Wih_r : Wih_l;
  const float* bih = dir ? bih_r : bih_l;
  float* GI = dir ? GIR : GIL;
  int c0 = (ct % 12) * 64, r0 = rt * 64;
  int tid = threadIdx.x, rg = tid & 7, cg = (tid >> 3) & 7;
  float acc[8][8];
  #pragma unroll
  for (int i=0;i<8;i++)
    #pragma unroll
    for (int j=0;j<8;j++) acc[i][j]=0.f;
  for (int kc = 0; kc < 4; kc++){
    __syncthreads();
    stage_t(Xs, CG + (size_t)r0*HH + kc*64, HH);
    stage_t(Ws, Wih + (size_t)c0*HH + kc*64, HH);
    __syncthreads();
    rg_inner(Xs, Ws, acc, rg, cg);
  }
  float bj[8];
  #pragma unroll
  for (int j=0;j<8;j++) bj[j] = bih[c0 + cg + 8*j];
  #pragma unroll
  for (int i=0;i<8;i++){
    int r = r0 + rg + 8*i;
    #pragma unroll
    for (int j=0;j<8;j++)
      GI[(size_t)r*768 + c0 + cg + 8*j] = acc[i][j] + bj[j];
  }
}

// ---------------- K7: GRU scans, 2D split + butterfly reduce --------------
// 64 blocks (b,dir) x 768 threads. Thread t: rows rg*8..+7, k-slice ks*32..+31.
// Whh fragment fp16-packed in 128 VGPRs; h fp16 in LDS (64 B/lane reads);
// shfl_xor halving butterfly sums the 8 k-slices -> lane t holds row t.
#if defined(__HIP_DEVICE_COMPILE__) && __has_builtin(__builtin_amdgcn_fdot2)
#define USE_FDOT2 1
#endif

__device__ __forceinline__ float dot2_acc(unsigned wb, unsigned hb, float a){
  half2_t wv = __builtin_bit_cast(half2_t, wb);
  half2_t hv = __builtin_bit_cast(half2_t, hb);
#ifdef USE_FDOT2
  return __builtin_amdgcn_fdot2(wv, hv, a, false);
#else
  return a + (float)wv.x*(float)hv.x + (float)wv.y*(float)hv.y;
#endif
}

__global__ __launch_bounds__(768, 3) void k7_scan(
    const float* __restrict__ GIL, const float* __restrict__ GIR,
    const float* __restrict__ Whh_l, const float* __restrict__ bhh_l,
    const float* __restrict__ Whh_r, const float* __restrict__ bhh_r,
    float* __restrict__ out)
{
  int b   = blockIdx.x >> 1;
  int dir = blockIdx.x & 1;
  int t   = threadIdx.x;
  int rg  = t >> 3;          // 0..95
  int ks  = t & 7;           // k-slice
  int r0  = rg * 8;
  int k0  = ks * 32;
  const float* GI  = dir ? GIR : GIL;
  const float* Whh = dir ? Whh_r : Whh_l;
  const float* bhh = dir ? bhh_r : bhh_l;

  unsigned w[128];           // w[i*16 + p]: rows r0+i, halves k0+2p,k0+2p+1
  #pragma unroll
  for (int i=0;i<8;i++){
    const float2* wr = (const float2*)(Whh + (size_t)(r0+i)*HH + k0);
    #pragma unroll
    for (int p=0;p<16;p++){
      float2 f = wr[p];
      half2_t hw = { (_Float16)f.x, (_Float16)f.y };
      w[i*16+p] = __builtin_bit_cast(unsigned, hw);
    }
  }
  float bias = bhh[t];

  __shared__ float gh[768];
  __shared__ __align__(16) unsigned short hs[256];
  if (t < 256) hs[t] = 0;

  float hprev = 0.f, gir=0.f, giz=0.f, gin=0.f;
  if (t < 256){
    const float* g = GI + ((size_t)b*LL + (dir ? (LL-1) : 0))*768;
    gir = g[t]; giz = g[t+256]; gin = g[t+512];
  }
  __syncthreads();

  for (int s = 0; s < LL; s++){
    int tt = dir ? (LL-1-s) : s;
    float a[8];
    #pragma unroll
    for (int i=0;i<8;i++) a[i] = 0.f;
    #pragma unroll
    for (int c=0;c<4;c++){
      uint4 q = ((const uint4*)hs)[ks*4 + c];
      unsigned hq[4] = {q.x, q.y, q.z, q.w};
      #pragma unroll
      for (int j=0;j<4;j++){
        #pragma unroll
        for (int i=0;i<8;i++)
          a[i] = dot2_acc(w[i*16 + c*4 + j], hq[j], a[i]);
      }
    }
    // butterfly over the 8 k-slices (consecutive lanes): lane t -> row t
    bool b4 = (ks & 4) != 0;
    float v0,v1,v2,v3;
    { float kp,sd;
      kp = b4? a[4]:a[0]; sd = b4? a[0]:a[4]; v0 = kp + __shfl_xor(sd, 4, 64);
      kp = b4? a[5]:a[1]; sd = b4? a[1]:a[5]; v1 = kp + __shfl_xor(sd, 4, 64);
      kp = b4? a[6]:a[2]; sd = b4? a[2]:a[6]; v2 = kp + __shfl_xor(sd, 4, 64);
      kp = b4? a[7]:a[3]; sd = b4? a[3]:a[7]; v3 = kp + __shfl_xor(sd, 4, 64);
    }
    bool b2 = (ks & 2) != 0;
    float u0,u1;
    { float kp,sd;
      kp = b2? v2:v0; sd = b2? v0:v2; u0 = kp + __shfl_xor(sd, 2, 64);
      kp = b2? v3:v1; sd = b2? v1:v3; u1 = kp + __shfl_xor(sd, 2, 64);
    }
    bool b1 = (ks & 1) != 0;
    float kp = b1? u1:u0, sd = b1? u0:u1;
    float ghv = kp + __shfl_xor(sd, 1, 64) + bias;
    gh[t] = ghv;

    // prefetch next step's gi while the barrier drains
    float ngr=0.f, ngz=0.f, ngn=0.f;
    if (t < 256 && s+1 < LL){
      int tn = dir ? (LL-2-s) : (s+1);
      const float* g = GI + ((size_t)b*LL + tn)*768;
      ngr = g[t]; ngz = g[t+256]; ngn = g[t+512];
    }
    __syncthreads();
    if (t < 256){
      float r = sigmoid_fast(gir + gh[t]);
      float z = sigmoid_fast(giz + gh[t+256]);
      float n = tanh_fast(gin + r*gh[t+512]);
      float hn = z*(hprev - n) + n;
      hprev = hn;
      out[((size_t)b*LL + tt)*(2*HH) + dir*HH + t] = hn;
      hs[t] = __builtin_bit_cast(unsigned short, (_Float16)hn);
      gir=ngr; giz=ngz; gin=ngn;
    }
    __syncthreads();
  }
}

extern "C" void kernel_launch(void* const* d_in, const int* in_sizes, int n_in,
                              void* d_out, int out_size, void* d_ws, size_t ws_size,
                              hipStream_t stream)
{
  const float* P    = (const float*)d_in[0];
  const float* wq_w = (const float*)d_in[1];
  const float* wq_b = (const float*)d_in[2];
  const float* wp_w = (const float*)d_in[3];
  const float* wp_b = (const float*)d_in[4];
  const float* ws_w = (const float*)d_in[5];
  // d_in[6] = ws_b: softmax-invariant, unused
  const float* wg_w = (const float*)d_in[7];
  const float* wg_b = (const float*)d_in[8];
  const float* Wih_l= (const float*)d_in[9];
  const float* Whh_l= (const float*)d_in[10];
  const float* bih_l= (const float*)d_in[11];
  const float* bhh_l= (const float*)d_in[12];
  const float* Wih_r= (const float*)d_in[13];
  const float* Whh_r= (const float*)d_in[14];
  const float* bih_r= (const float*)d_in[15];
  const float* bhh_r= (const float*)d_in[16];

  float* ws  = (float*)d_ws;
  // Workspace (floats), same 151 MB layout as R1:
  float* HQ  = ws;                    //  4,194,304
  float* PP  = ws + 4194304;          //  4,194,304
  float* S   = ws + 8388608;          //  8,388,608
  float* C   = ws + 16777216;         //  4,194,304
  float* CG  = ws + 20971520;         //  4,194,304
  float* GIR = ws + 25165824;         // 12,582,912
  float* GIL = ws;                    // 12,582,912 (aliases HQ/PP/S-front; dead by k6)
  float* out = (float*)d_out;

  k1_hq_pp  <<<dim3(256, 8),    256, 0, stream>>>(P, wq_w, wq_b, wp_w, wp_b, HQ, PP);
  k2_scores <<<dim3(16, 32),    256, 0, stream>>>(HQ, PP, ws_w, S);
  k3_softmax<<<4096,            256, 0, stream>>>(S);
  k4_context<<<dim3(4, 8, 32),  256, 0, stream>>>(S, P, C);
  k5_gate   <<<dim3(256, 4),    256, 0, stream>>>(P, C, wg_w, wg_b, CG);
  k6_gi     <<<dim3(256, 24),   256, 0, stream>>>(CG, Wih_l, bih_l, Wih_r, bih_r, GIL, GIR);
  k7_scan   <<<64,              768, 0, stream>>>(GIL, GIR, Whh_l, bhh_l, Whh_r, bhh_r, out);
}

// Round 3
// 1627.331 us; speedup vs baseline: 1.4670x; 1.4670x over previous
//
#include <hip/hip_runtime.h>
#include <cstdint>

// SelfMatchingLayer: B=32, L=512, H=256, fp32.
// R3: (a) k7: no global ops inside the per-step loop (gi staged to LDS per
//     32-step chunk, out buffered in LDS) -> barriers drain lgkm only, not
//     a full HBM latency; weight regs fit in VGPRs (no AGPR bounce).
//     (b) k1/k4/k5/k6: fix R2's 4x-redundant thread mapping (64 combos for
//     256 threads); now 128x128 tiles, 16x16 thread grid, 8x8 regs/thread,
//     b128 LDS reads at stride 132 (conflict-free, 16B-aligned).

#define LL 512
#define HH 256

typedef _Float16 half2_t __attribute__((ext_vector_type(2)));

__device__ __forceinline__ float exp2f_fast(float x){
#if defined(__HIP_DEVICE_COMPILE__)
  return __builtin_amdgcn_exp2f(x);
#else
  return exp2f(x);
#endif
}
__device__ __forceinline__ float rcpf_fast(float x){
#if defined(__HIP_DEVICE_COMPILE__)
  return __builtin_amdgcn_rcpf(x);
#else
  return 1.0f/x;
#endif
}
__device__ __forceinline__ float tanh_fast(float x){
  float e = exp2f_fast(x * 2.885390081777927f);   // 2*log2(e)
  return 1.0f - 2.0f * rcpf_fast(1.0f + e);
}
__device__ __forceinline__ float sigmoid_fast(float x){
  return rcpf_fast(1.0f + exp2f_fast(x * -1.4426950408889634f));
}

#define SCALE_K2 2.885390081777927f   // 2*log2(e)

// ==== 128x128-tile GEMM helpers ==========================================
// LDS layout: Ls[k*132 + e], k in [0,64), e in [0,128). 132*4B: 16B-aligned
// rows; bank = (4k + e) % 32.
// stage_t128: transpose global [row][k] -> Ls[k][row]
__device__ __forceinline__ void stage_t128(float* Ls, const float* g, int ldg){
  int tid = threadIdx.x;
  int r = tid >> 4, kq = (tid & 15) * 4;
  #pragma unroll
  for (int it = 0; it < 8; it++){
    int rr = r + 16*it;
    float4 v = *(const float4*)(g + (size_t)rr*ldg + kq);
    Ls[(kq+0)*132 + rr] = v.x;
    Ls[(kq+1)*132 + rr] = v.y;
    Ls[(kq+2)*132 + rr] = v.z;
    Ls[(kq+3)*132 + rr] = v.w;
  }
}
// stage_d128: global [k][e] -> Ls[k][e] (b128 both sides)
__device__ __forceinline__ void stage_d128(float* Ls, const float* g, int ldg){
  int tid = threadIdx.x;
  int k = tid >> 5, eq = (tid & 31) * 4;
  #pragma unroll
  for (int it = 0; it < 8; it++){
    int kk = k + 8*it;
    float4 v = *(const float4*)(g + (size_t)kk*ldg + eq);
    *(float4*)(Ls + kk*132 + eq) = v;
  }
}
// rows of thread: rg*4+{0..3} and 64+rg*4+{0..3}; cols: cg*4+{0..3}, +64.
__device__ __forceinline__ void rg_inner128(const float* Xs, const float* Ws,
                                            float (&acc)[8][8], int rg, int cg){
  #pragma unroll 2
  for (int k = 0; k < 64; k++){
    const float* xr = Xs + k*132;
    const float* wr = Ws + k*132;
    float4 x0 = *(const float4*)(xr + rg*4);
    float4 x1 = *(const float4*)(xr + 64 + rg*4);
    float4 w0 = *(const float4*)(wr + cg*4);
    float4 w1 = *(const float4*)(wr + 64 + cg*4);
    float xv[8] = {x0.x,x0.y,x0.z,x0.w, x1.x,x1.y,x1.z,x1.w};
    float wv[8] = {w0.x,w0.y,w0.z,w0.w, w1.x,w1.y,w1.z,w1.w};
    #pragma unroll
    for (int i=0;i<8;i++)
      #pragma unroll
      for (int j=0;j<8;j++)
        acc[i][j] = fmaf(xv[i], wv[j], acc[i][j]);
  }
}
#define ROW_OF(i, rg) ((rg)*4 + ((i)&3) + ((i)>>2)*64)
#define COL_OF(j, cg) ((cg)*4 + ((j)&3) + ((j)>>2)*64)

// ---------------- K1: HQ' = SC*(P@wq^T+bq) ; PP' = SC*(P@wp^T+bp) --------
// grid (128 row-tiles, 4): ct<2 -> wq/HQ, else wp/PP.
__global__ __launch_bounds__(256) void k1_hq_pp(
    const float* __restrict__ P,
    const float* __restrict__ wq_w, const float* __restrict__ wq_b,
    const float* __restrict__ wp_w, const float* __restrict__ wp_b,
    float* __restrict__ HQ, float* __restrict__ PP)
{
  __shared__ __align__(16) float Xs[64*132];
  __shared__ __align__(16) float Ws[64*132];
  int rt = blockIdx.x, ct = blockIdx.y;
  const float* W  = (ct < 2) ? wq_w : wp_w;
  const float* Bv = (ct < 2) ? wq_b : wp_b;
  float* O = (ct < 2) ? HQ : PP;
  int c0 = (ct & 1) * 128, r0 = rt * 128;
  int tid = threadIdx.x, rg = tid & 15, cg = tid >> 4;
  float acc[8][8];
  #pragma unroll
  for (int i=0;i<8;i++)
    #pragma unroll
    for (int j=0;j<8;j++) acc[i][j]=0.f;
  for (int kc = 0; kc < 4; kc++){
    __syncthreads();
    stage_t128(Xs, P + (size_t)r0*HH + kc*64, HH);
    stage_t128(Ws, W + (size_t)c0*HH + kc*64, HH);
    __syncthreads();
    rg_inner128(Xs, Ws, acc, rg, cg);
  }
  float bj[8];
  #pragma unroll
  for (int j=0;j<8;j++) bj[j] = Bv[c0 + COL_OF(j,cg)];
  #pragma unroll
  for (int i=0;i<8;i++){
    int r = r0 + ROW_OF(i,rg);
    #pragma unroll
    for (int j=0;j<8;j++)
      O[(size_t)r*HH + c0 + COL_OF(j,cg)] = SCALE_K2 * (acc[i][j] + bj[j]);
  }
}

// ---------------- K2: S_eff[b,t,l] = -2 * sum_h w_h / (1 + exp2(HQ'+PP')) -
// grid (16 t-tiles, 32 b); per-thread 8t x 2l tile. (unchanged from R2)
__global__ __launch_bounds__(256) void k2_scores(
    const float* __restrict__ HQ, const float* __restrict__ PP,
    const float* __restrict__ ws_w, float* __restrict__ S)
{
  __shared__ float Hq_c[128*65];
  __shared__ float Pp_c[32*65];
  __shared__ float wsl[256];
  int tid = threadIdx.x;
  int b = blockIdx.y, t0 = blockIdx.x * 32;
  wsl[tid] = ws_w[tid];
  int tg = tid >> 6;
  int lg = tid & 63;
  for (int lc = 0; lc < 4; lc++){
    float acc[8][2];
    #pragma unroll
    for (int i=0;i<8;i++){ acc[i][0]=0.f; acc[i][1]=0.f; }
    for (int hc = 0; hc < 4; hc++){
      __syncthreads();
      {
        int r = tid >> 4, kq = (tid & 15) * 4;
        #pragma unroll
        for (int it=0; it<2; it++){
          int t = r + 16*it;
          float4 v = *(const float4*)(PP + ((size_t)b*LL + t0 + t)*HH + hc*64 + kq);
          float* d = Pp_c + t*65 + kq;
          d[0]=v.x; d[1]=v.y; d[2]=v.z; d[3]=v.w;
        }
      }
      {
        int r = tid >> 4, kq = (tid & 15) * 4;
        #pragma unroll
        for (int it=0; it<8; it++){
          int l = r + 16*it;
          float4 v = *(const float4*)(HQ + ((size_t)b*LL + lc*128 + l)*HH + hc*64 + kq);
          float* d = Hq_c + l*65 + kq;
          d[0]=v.x; d[1]=v.y; d[2]=v.z; d[3]=v.w;
        }
      }
      __syncthreads();
      #pragma unroll 2
      for (int h = 0; h < 64; h++){
        float w = wsl[hc*64 + h];
        float pp[8], hq[2];
        #pragma unroll
        for (int i=0;i<8;i++) pp[i] = Pp_c[(tg + 4*i)*65 + h];
        #pragma unroll
        for (int j=0;j<2;j++) hq[j] = Hq_c[(2*lg + j)*65 + h];
        #pragma unroll
        for (int i=0;i<8;i++)
          #pragma unroll
          for (int j=0;j<2;j++){
            float e = exp2f_fast(pp[i] + hq[j]);
            acc[i][j] = fmaf(w, rcpf_fast(1.0f + e), acc[i][j]);
          }
      }
    }
    #pragma unroll
    for (int i=0;i<8;i++)
      #pragma unroll
      for (int j=0;j<2;j++)
        S[((size_t)b*LL + t0 + tg + 4*i)*LL + lc*128 + 2*lg + j] = -2.0f*acc[i][j];
    __syncthreads();
  }
}

// ---------------- K3: softmax over l, in place; one wave per row ----------
__global__ __launch_bounds__(256) void k3_softmax(float* __restrict__ S)
{
  int wave = threadIdx.x >> 6, lane = threadIdx.x & 63;
  size_t row = (size_t)blockIdx.x*4 + wave;
  float* p = S + row*LL;
  float v[8];
  #pragma unroll
  for (int i=0;i<8;i++) v[i] = p[lane + 64*i];
  float m = v[0];
  #pragma unroll
  for (int i=1;i<8;i++) m = fmaxf(m, v[i]);
  #pragma unroll
  for (int off=32; off>=1; off>>=1) m = fmaxf(m, __shfl_xor(m, off, 64));
  float s = 0.f;
  #pragma unroll
  for (int i=0;i<8;i++){ v[i] = exp2f_fast((v[i]-m)*1.4426950408889634f); s += v[i]; }
  #pragma unroll
  for (int off=32; off>=1; off>>=1) s += __shfl_xor(s, off, 64);
  float inv = 1.0f / s;
  #pragma unroll
  for (int i=0;i<8;i++) p[lane + 64*i] = v[i]*inv;
}

// ---------------- K4: C[b,t,:] = attn[b,t,:] @ P[b,:,:] -------------------
// grid (2 j-tiles, 4 t-tiles, 32 b); K = l = 512 in 8 chunks.
__global__ __launch_bounds__(256) void k4_context(
    const float* __restrict__ S, const float* __restrict__ P, float* __restrict__ C)
{
  __shared__ __align__(16) float As[64*132];
  __shared__ __align__(16) float Ps[64*132];
  int j0 = blockIdx.x * 128, t0 = blockIdx.y * 128, b = blockIdx.z;
  int tid = threadIdx.x, rg = tid & 15, cg = tid >> 4;
  float acc[8][8];
  #pragma unroll
  for (int i=0;i<8;i++)
    #pragma unroll
    for (int j=0;j<8;j++) acc[i][j]=0.f;
  for (int lc = 0; lc < 8; lc++){
    int l0 = lc*64;
    __syncthreads();
    stage_t128(As, S + ((size_t)b*LL + t0)*LL + l0, LL);   // As[l][t]
    stage_d128(Ps, P + ((size_t)b*LL + l0)*HH + j0, HH);   // Ps[l][j]
    __syncthreads();
    rg_inner128(As, Ps, acc, rg, cg);
  }
  #pragma unroll
  for (int i=0;i<8;i++){
    int t = t0 + ROW_OF(i,rg);
    #pragma unroll
    for (int j=0;j<8;j++)
      C[((size_t)b*LL + t)*HH + j0 + COL_OF(j,cg)] = acc[i][j];
  }
}

// ---------------- K5: Cg = sigmoid([P|C]@wg^T + bg) * C -------------------
// grid (128 row-tiles, 2 col-tiles). K = 512 (P then C).
__global__ __launch_bounds__(256) void k5_gate(
    const float* __restrict__ P, const float* __restrict__ C,
    const float* __restrict__ wg_w, const float* __restrict__ wg_b,
    float* __restrict__ CG)
{
  __shared__ __align__(16) float Xs[64*132];
  __shared__ __align__(16) float Ws[64*132];
  int r0 = blockIdx.x*128, c0 = blockIdx.y*128;
  int tid = threadIdx.x, rg = tid & 15, cg = tid >> 4;
  float acc[8][8];
  #pragma unroll
  for (int i=0;i<8;i++)
    #pragma unroll
    for (int j=0;j<8;j++) acc[i][j]=0.f;
  for (int kc = 0; kc < 8; kc++){
    const float* Xsrc = (kc < 4) ? (P + (size_t)r0*HH + kc*64)
                                 : (C + (size_t)r0*HH + (kc-4)*64);
    __syncthreads();
    stage_t128(Xs, Xsrc, HH);
    stage_t128(Ws, wg_w + (size_t)c0*(2*HH) + kc*64, 2*HH);
    __syncthreads();
    rg_inner128(Xs, Ws, acc, rg, cg);
  }
  float bj[8];
  #pragma unroll
  for (int j=0;j<8;j++) bj[j] = wg_b[c0 + COL_OF(j,cg)];
  #pragma unroll
  for (int i=0;i<8;i++){
    int r = r0 + ROW_OF(i,rg);
    #pragma unroll
    for (int j=0;j<8;j++){
      int c = c0 + COL_OF(j,cg);
      float g = sigmoid_fast(acc[i][j] + bj[j]);
      CG[(size_t)r*HH + c] = g * C[(size_t)r*HH + c];
    }
  }
}

// ---------------- K6: GI_{l,r} = Cg @ Wih^T + bih -------------------------
// grid (128 row-tiles, 12 col-tiles): ct<6 left, else right.
__global__ __launch_bounds__(256) void k6_gi(
    const float* __restrict__ CG,
    const float* __restrict__ Wih_l, const float* __restrict__ bih_l,
    const float* __restrict__ Wih_r, const float* __restrict__ bih_r,
    float* __restrict__ GIL, float* __restrict__ GIR)
{
  __shared__ __align__(16) float Xs[64*132];
  __shared__ __align__(16) float Ws[64*132];
  int rt = blockIdx.x, ct = blockIdx.y;
  int dir = (ct >= 6);
  const float* Wih = dir ? Wih_r : Wih_l;
  const float* bih = dir ? bih_r : bih_l;
  float* GI = dir ? GIR : GIL;
  int c0 = (ct % 6) * 128, r0 = rt * 128;
  int tid = threadIdx.x, rg = tid & 15, cg = tid >> 4;
  float acc[8][8];
  #pragma unroll
  for (int i=0;i<8;i++)
    #pragma unroll
    for (int j=0;j<8;j++) acc[i][j]=0.f;
  for (int kc = 0; kc < 4; kc++){
    __syncthreads();
    stage_t128(Xs, CG + (size_t)r0*HH + kc*64, HH);
    stage_t128(Ws, Wih + (size_t)c0*HH + kc*64, HH);
    __syncthreads();
    rg_inner128(Xs, Ws, acc, rg, cg);
  }
  float bj[8];
  #pragma unroll
  for (int j=0;j<8;j++) bj[j] = bih[c0 + COL_OF(j,cg)];
  #pragma unroll
  for (int i=0;i<8;i++){
    int r = r0 + ROW_OF(i,rg);
    #pragma unroll
    for (int j=0;j<8;j++)
      GI[(size_t)r*768 + c0 + COL_OF(j,cg)] = acc[i][j] + bj[j];
  }
}

// ---------------- K7: GRU scans -------------------------------------------
// 64 blocks (b,dir) x 768 threads. Thread t: rows (t>>3)*8..+7, k-slice
// (t&7)*32..+31; fp16 weights in 128 VGPRs; butterfly reduce over 8 slices.
// NO global memory ops inside the step loop: gi staged to LDS per 32-step
// chunk, outputs buffered in LDS and flushed per chunk.
#if defined(__HIP_DEVICE_COMPILE__) && __has_builtin(__builtin_amdgcn_fdot2)
#define USE_FDOT2 1
#endif

__device__ __forceinline__ float dot2_acc(unsigned wb, unsigned hb, float a){
  half2_t wv = __builtin_bit_cast(half2_t, wb);
  half2_t hv = __builtin_bit_cast(half2_t, hb);
#ifdef USE_FDOT2
  return __builtin_amdgcn_fdot2(wv, hv, a, false);
#else
  return a + (float)wv.x*(float)hv.x + (float)wv.y*(float)hv.y;
#endif
}

__global__ __launch_bounds__(768, 3) void k7_scan(
    const float* __restrict__ GIL, const float* __restrict__ GIR,
    const float* __restrict__ Whh_l, const float* __restrict__ bhh_l,
    const float* __restrict__ Whh_r, const float* __restrict__ bhh_r,
    float* __restrict__ out)
{
  int b   = blockIdx.x >> 1;
  int dir = blockIdx.x & 1;
  int t   = threadIdx.x;
  int rg  = t >> 3;          // 0..95
  int ks  = t & 7;           // k-slice
  int r0  = rg * 8;
  int k0  = ks * 32;
  const float* GI  = dir ? GIR : GIL;
  const float* Whh = dir ? Whh_r : Whh_l;
  const float* bhh = dir ? bhh_r : bhh_l;

  unsigned w[128];           // w[i*16+p]: row r0+i, halves k0+2p, k0+2p+1
  #pragma unroll
  for (int i=0;i<8;i++){
    const float2* wr = (const float2*)(Whh + (size_t)(r0+i)*HH + k0);
    #pragma unroll
    for (int p=0;p<16;p++){
      float2 f = wr[p];
      half2_t hw = { (_Float16)f.x, (_Float16)f.y };
      w[i*16+p] = __builtin_bit_cast(unsigned, hw);
    }
  }
  float bias = bhh[t];

  __shared__ float gh[768];
  __shared__ __align__(16) unsigned short hs[256];
  __shared__ __align__(16) float gi_buf[32*768];   // 96 KB
  __shared__ __align__(16) float out_buf[32*256];  // 32 KB
  if (t < 256) hs[t] = 0;

  float hprev = 0.f;

  for (int chunk = 0; chunk < 16; chunk++){
    int s0 = chunk * 32;
    int tlo = dir ? (LL - s0 - 32) : s0;    // staged t range [tlo, tlo+31]
    // stage 32 steps of gi (contiguous in t): 6144 float4
    {
      const float4* src = (const float4*)(GI + ((size_t)b*LL + tlo)*768);
      float4* dst = (float4*)gi_buf;
      #pragma unroll
      for (int i = 0; i < 8; i++)
        dst[t + 768*i] = src[t + 768*i];
    }
    __syncthreads();   // gi_buf ready; hs from prev step visible

    for (int p = 0; p < 32; p++){
      int s = s0 + p;
      int tt = dir ? (LL-1-s) : s;
      int gidx = tt - tlo;                  // 0..31
      float a[8];
      #pragma unroll
      for (int i=0;i<8;i++) a[i] = 0.f;
      #pragma unroll
      for (int c=0;c<4;c++){
        uint4 q = ((const uint4*)hs)[ks*4 + c];
        unsigned hq[4] = {q.x, q.y, q.z, q.w};
        #pragma unroll
        for (int j=0;j<4;j++){
          #pragma unroll
          for (int i=0;i<8;i++)
            a[i] = dot2_acc(w[i*16 + c*4 + j], hq[j], a[i]);
        }
      }
      // butterfly over the 8 k-slices (lane low bits): lane t -> row t
      bool b4 = (ks & 4) != 0;
      float v0,v1,v2,v3;
      { float kp,sd;
        kp = b4? a[4]:a[0]; sd = b4? a[0]:a[4]; v0 = kp + __shfl_xor(sd, 4, 64);
        kp = b4? a[5]:a[1]; sd = b4? a[1]:a[5]; v1 = kp + __shfl_xor(sd, 4, 64);
        kp = b4? a[6]:a[2]; sd = b4? a[2]:a[6]; v2 = kp + __shfl_xor(sd, 4, 64);
        kp = b4? a[7]:a[3]; sd = b4? a[3]:a[7]; v3 = kp + __shfl_xor(sd, 4, 64);
      }
      bool b2 = (ks & 2) != 0;
      float u0,u1;
      { float kp,sd;
        kp = b2? v2:v0; sd = b2? v0:v2; u0 = kp + __shfl_xor(sd, 2, 64);
        kp = b2? v3:v1; sd = b2? v1:v3; u1 = kp + __shfl_xor(sd, 2, 64);
      }
      bool b1 = (ks & 1) != 0;
      float kp = b1? u1:u0, sd = b1? u0:u1;
      gh[t] = kp + __shfl_xor(sd, 1, 64) + bias;
      __syncthreads();                      // lgkm-only drain
      if (t < 256){
        const float* g = gi_buf + (size_t)gidx*768;
        float r = sigmoid_fast(g[t]     + gh[t]);
        float z = sigmoid_fast(g[t+256] + gh[t+256]);
        float n = tanh_fast  (g[t+512] + r*gh[t+512]);
        float hn = z*(hprev - n) + n;
        hprev = hn;
        out_buf[p*256 + t] = hn;
        hs[t] = __builtin_bit_cast(unsigned short, (_Float16)hn);
      }
      __syncthreads();                      // lgkm-only drain
    }
    // flush outputs for this chunk (coalesced 256-wide per step)
    for (int i = t; i < 32*256; i += 768){
      int p = i >> 8, u = i & 255;
      int s = s0 + p;
      int tt = dir ? (LL-1-s) : s;
      out[((size_t)b*LL + tt)*(2*HH) + dir*HH + u] = out_buf[i];
    }
    __syncthreads();   // out_buf/gi_buf safe to reuse
  }
}

extern "C" void kernel_launch(void* const* d_in, const int* in_sizes, int n_in,
                              void* d_out, int out_size, void* d_ws, size_t ws_size,
                              hipStream_t stream)
{
  const float* P    = (const float*)d_in[0];
  const float* wq_w = (const float*)d_in[1];
  const float* wq_b = (const float*)d_in[2];
  const float* wp_w = (const float*)d_in[3];
  const float* wp_b = (const float*)d_in[4];
  const float* ws_w = (const float*)d_in[5];
  // d_in[6] = ws_b: softmax-invariant, unused
  const float* wg_w = (const float*)d_in[7];
  const float* wg_b = (const float*)d_in[8];
  const float* Wih_l= (const float*)d_in[9];
  const float* Whh_l= (const float*)d_in[10];
  const float* bih_l= (const float*)d_in[11];
  const float* bhh_l= (const float*)d_in[12];
  const float* Wih_r= (const float*)d_in[13];
  const float* Whh_r= (const float*)d_in[14];
  const float* bih_r= (const float*)d_in[15];
  const float* bhh_r= (const float*)d_in[16];

  float* ws  = (float*)d_ws;
  // Workspace (floats), 151 MB:
  float* HQ  = ws;                    //  4,194,304
  float* PP  = ws + 4194304;          //  4,194,304
  float* S   = ws + 8388608;          //  8,388,608
  float* C   = ws + 16777216;         //  4,194,304
  float* CG  = ws + 20971520;         //  4,194,304
  float* GIR = ws + 25165824;         // 12,582,912
  float* GIL = ws;                    // 12,582,912 (aliases HQ/PP/S-front; dead by k6)
  float* out = (float*)d_out;

  k1_hq_pp  <<<dim3(128, 4),    256, 0, stream>>>(P, wq_w, wq_b, wp_w, wp_b, HQ, PP);
  k2_scores <<<dim3(16, 32),    256, 0, stream>>>(HQ, PP, ws_w, S);
  k3_softmax<<<4096,            256, 0, stream>>>(S);
  k4_context<<<dim3(2, 4, 32),  256, 0, stream>>>(S, P, C);
  k5_gate   <<<dim3(128, 2),    256, 0, stream>>>(P, C, wg_w, wg_b, CG);
  k6_gi     <<<dim3(128, 12),   256, 0, stream>>>(CG, Wih_l, bih_l, Wih_r, bih_r, GIL, GIR);
  k7_scan   <<<64,              768, 0, stream>>>(GIL, GIR, Whh_l, bhh_l, Whh_r, bhh_r, out);
}